// Round 3
// baseline (596.747 us; speedup 1.0000x reference)
//
#include <hip/hip_runtime.h>
#include <cstddef>

#define Hdim 1024
#define Bdim 64
#define Idim 128

// BETA = 10.0 / 0.192
#define BETA_F 52.083333333333336f
#define INV_BETA_F 0.0192f
#define LN2_F 0.6931471805599453f

__device__ __forceinline__ float sigf(float x) {
    return 1.0f / (1.0f + __expf(-x));
}

// log(cosh(t)) = |t| + log1p(exp(-2|t|)) - ln2   (stable, matches fp32 ref)
__device__ __forceinline__ float logcoshf_(float t) {
    float a = fabsf(t);
    return a + log1pf(__expf(-2.0f * a)) - LN2_F;
}

// ---------------------------------------------------------------------------
// Pre-kernel: rates r = sigmoid(v_t)  (flat B*H),
// and x-projections: membx[j,b] = p_r@x + b_r ; gatex[j,b] = |p_r|@x + g_z
// grid = H blocks of B threads.
// ---------------------------------------------------------------------------
__global__ void pre_kernel(const float* __restrict__ x,
                           const float* __restrict__ v_t,
                           const float* __restrict__ p_r,
                           const float* __restrict__ b_r,
                           const float* __restrict__ g_z,
                           float* __restrict__ r_ws,
                           float* __restrict__ membx,
                           float* __restrict__ gatex) {
    const int j = blockIdx.x;   // 0..H-1
    const int b = threadIdx.x;  // 0..B-1
    const float* pr = p_r + (size_t)j * Idim;
    float accm = 0.0f, accg = 0.0f;
#pragma unroll 4
    for (int i = 0; i < Idim; ++i) {
        float p  = pr[i];              // wave-uniform -> scalar load
        float xv = x[i * Bdim + b];    // coalesced
        accm = fmaf(p, xv, accm);
        accg = fmaf(fabsf(p), xv, accg);
    }
    membx[j * Bdim + b] = accm + b_r[j];
    gatex[j * Bdim + b] = accg + g_z[j];

    int id = j * Bdim + b;  // flat elementwise over B*H
    r_ws[id] = sigf(v_t[id]);
}

// ---------------------------------------------------------------------------
// Transform kernel: elementwise over H*H, computes
//   t_wr = logcosh(beta*raw)/beta ; t_zx/t_zu = 0.001+0.099*sig(c) ;
//   t_uc = 0.9*sig(c_U)
// so the streaming kernel has zero transcendentals.
// ---------------------------------------------------------------------------
__global__ __launch_bounds__(256) void transform_kernel(
    const float* __restrict__ raw_w_r,
    const float* __restrict__ c_x,
    const float* __restrict__ c_u,
    const float* __restrict__ c_U,
    float* __restrict__ t_wr,
    float* __restrict__ t_zx,
    float* __restrict__ t_zu,
    float* __restrict__ t_uc) {
    const int i = (blockIdx.x * 256 + threadIdx.x) * 4;  // < H*H
    float4 rw = *(const float4*)(raw_w_r + i);
    float4 cx = *(const float4*)(c_x + i);
    float4 cu = *(const float4*)(c_u + i);
    float4 cN = *(const float4*)(c_U + i);
    float4 o;
    o.x = logcoshf_(BETA_F * rw.x) * INV_BETA_F;
    o.y = logcoshf_(BETA_F * rw.y) * INV_BETA_F;
    o.z = logcoshf_(BETA_F * rw.z) * INV_BETA_F;
    o.w = logcoshf_(BETA_F * rw.w) * INV_BETA_F;
    *(float4*)(t_wr + i) = o;
    o.x = 0.001f + 0.099f * sigf(cx.x);
    o.y = 0.001f + 0.099f * sigf(cx.y);
    o.z = 0.001f + 0.099f * sigf(cx.z);
    o.w = 0.001f + 0.099f * sigf(cx.w);
    *(float4*)(t_zx + i) = o;
    o.x = 0.001f + 0.099f * sigf(cu.x);
    o.y = 0.001f + 0.099f * sigf(cu.y);
    o.z = 0.001f + 0.099f * sigf(cu.z);
    o.w = 0.001f + 0.099f * sigf(cu.w);
    *(float4*)(t_zu + i) = o;
    o.x = 0.9f * sigf(cN.x);
    o.y = 0.9f * sigf(cN.y);
    o.z = 0.9f * sigf(cN.z);
    o.w = 0.9f * sigf(cN.w);
    *(float4*)(t_uc + i) = o;
}

// ---------------------------------------------------------------------------
// Main kernel: pure streaming, no LDS, no barriers. Grid (32, 256):
//   blockIdx.x = batch-pair group (b0 = 2*x), blockIdx.y = j-quad.
// Each of the 4 waves owns one j-row and streams 2 batches' X/U rows
// (coalesced 1 KB float4 wave-loads), with param rows hitting L2/L3.
// PRECOMP=false fallback computes transcendentals inline (if ws too small).
// ---------------------------------------------------------------------------
template <bool PRECOMP>
__global__ __launch_bounds__(256, 8) void main_kernel(
    const float* __restrict__ X,
    const float* __restrict__ U,
    const float* __restrict__ pw_,   // t_wr  (or raw_w_r if !PRECOMP)
    const float* __restrict__ pzx_,  // t_zx  (or c_x)
    const float* __restrict__ pzu_,  // t_zu  (or c_u)
    const float* __restrict__ puc_,  // t_uc  (or c_U)
    const float* __restrict__ v_t,
    const float* __restrict__ a_exc,
    const float* __restrict__ a_inh,
    const float* __restrict__ r_ws,
    const float* __restrict__ membx,
    const float* __restrict__ gatex,
    float* __restrict__ out) {
    const int wave = threadIdx.x >> 6;
    const int lane = threadIdx.x & 63;
    const int j    = blockIdx.y * 4 + wave;
    const int b0   = blockIdx.x * 2;

    const size_t prow = (size_t)j * Hdim;
    const float* pw  = pw_  + prow;
    const float* pzx = pzx_ + prow;
    const float* pzu = pzu_ + prow;
    const float* puc = puc_ + prow;

    const float* X0 = X + ((size_t)b0 * Hdim + j) * Hdim;
    const float* X1 = X0 + (size_t)Hdim * Hdim;
    const float* U0 = U + ((size_t)b0 * Hdim + j) * Hdim;
    const float* U1 = U0 + (size_t)Hdim * Hdim;
    const float* rr0 = r_ws + b0 * Hdim;
    const float* rr1 = rr0 + Hdim;

    const float rj0 = rr0[j];
    const float rj1 = rr1[j];

    float rec0 = 0.f, rec1 = 0.f;
    float ge0 = 0.f, ge1 = 0.f;   // gate partial, k < 512 (excitatory)
    float gi0 = 0.f, gi1 = 0.f;   // gate partial, k >= 512 (inhibitory)

#pragma unroll
    for (int chunk = 0; chunk < 4; ++chunk) {
        const int k = (chunk * 64 + lane) * 4;
        float4 wr, zx, zu, uc;
        if (PRECOMP) {
            wr = *(const float4*)(pw + k);
            zx = *(const float4*)(pzx + k);
            zu = *(const float4*)(pzu + k);
            uc = *(const float4*)(puc + k);
        } else {
            float4 rw = *(const float4*)(pw + k);
            float4 cx = *(const float4*)(pzx + k);
            float4 cu = *(const float4*)(pzu + k);
            float4 cN = *(const float4*)(puc + k);
            wr.x = logcoshf_(BETA_F * rw.x) * INV_BETA_F;
            wr.y = logcoshf_(BETA_F * rw.y) * INV_BETA_F;
            wr.z = logcoshf_(BETA_F * rw.z) * INV_BETA_F;
            wr.w = logcoshf_(BETA_F * rw.w) * INV_BETA_F;
            zx.x = 0.001f + 0.099f * sigf(cx.x);
            zx.y = 0.001f + 0.099f * sigf(cx.y);
            zx.z = 0.001f + 0.099f * sigf(cx.z);
            zx.w = 0.001f + 0.099f * sigf(cx.w);
            zu.x = 0.001f + 0.099f * sigf(cu.x);
            zu.y = 0.001f + 0.099f * sigf(cu.y);
            zu.z = 0.001f + 0.099f * sigf(cu.z);
            zu.w = 0.001f + 0.099f * sigf(cu.w);
            uc.x = 0.9f * sigf(cN.x);
            uc.y = 0.9f * sigf(cN.y);
            uc.z = 0.9f * sigf(cN.z);
            uc.w = 0.9f * sigf(cN.w);
        }
        float4 r0 = *(const float4*)(rr0 + k);
        float4 r1 = *(const float4*)(rr1 + k);
        float4 Xv0 = *(const float4*)(X0 + k);
        float4 Uv0 = *(const float4*)(U0 + k);
        float4 Xv1 = *(const float4*)(X1 + k);
        float4 Uv1 = *(const float4*)(U1 + k);

        float g0 = 0.f, g1 = 0.f;
#define COMPONENT(c)                                                          \
    {                                                                         \
        float xn0 = zx.c + (1.0f - zx.c) * Xv0.c - Uv0.c * Xv0.c * rj0;       \
        float un0 = uc.c * zu.c + (1.0f - zu.c) * Uv0.c +                     \
                    uc.c * (1.0f - Uv0.c) * rj0;                              \
        un0 = fminf(fmaxf(un0, uc.c), 1.0f);                                  \
        rec0 = fmaf(xn0 * un0 * wr.c, r0.c, rec0);                            \
        g0   = fmaf(wr.c, r0.c, g0);                                          \
        float xn1 = zx.c + (1.0f - zx.c) * Xv1.c - Uv1.c * Xv1.c * rj1;       \
        float un1 = uc.c * zu.c + (1.0f - zu.c) * Uv1.c +                     \
                    uc.c * (1.0f - Uv1.c) * rj1;                              \
        un1 = fminf(fmaxf(un1, uc.c), 1.0f);                                  \
        rec1 = fmaf(xn1 * un1 * wr.c, r1.c, rec1);                            \
        g1   = fmaf(wr.c, r1.c, g1);                                          \
    }
        COMPONENT(x)
        COMPONENT(y)
        COMPONENT(z)
        COMPONENT(w)
#undef COMPONENT
        if (chunk < 2) { ge0 += g0; ge1 += g1; }
        else           { gi0 += g0; gi1 += g1; }
    }

    // fold Dale gains, then butterfly-reduce 4 values across the wave
    const float Aexc = 10.0f * sigf(a_exc[0]);
    const float Ainh = 10.0f * sigf(a_inh[0]);
    float gate0 = fmaf(Aexc, ge0, Ainh * gi0);
    float gate1 = fmaf(Aexc, ge1, Ainh * gi1);

#pragma unroll
    for (int off = 32; off > 0; off >>= 1) {
        rec0  += __shfl_xor(rec0, off, 64);
        rec1  += __shfl_xor(rec1, off, 64);
        gate0 += __shfl_xor(gate0, off, 64);
        gate1 += __shfl_xor(gate1, off, 64);
    }

    if (lane == 0) {
        {
            float z  = 0.1f * sigf(gate0 + gatex[j * Bdim + b0]);
            float vt = v_t[(size_t)b0 * Hdim + j];
            out[(size_t)b0 * Hdim + j] =
                (1.0f - z) * vt + 0.1f * (rec0 + membx[j * Bdim + b0]);
        }
        {
            const int b = b0 + 1;
            float z  = 0.1f * sigf(gate1 + gatex[j * Bdim + b]);
            float vt = v_t[(size_t)b * Hdim + j];
            out[(size_t)b * Hdim + j] =
                (1.0f - z) * vt + 0.1f * (rec1 + membx[j * Bdim + b]);
        }
    }
}

extern "C" void kernel_launch(void* const* d_in, const int* in_sizes, int n_in,
                              void* d_out, int out_size, void* d_ws, size_t ws_size,
                              hipStream_t stream) {
    const float* x       = (const float*)d_in[0];   // (I,B)
    const float* v_t     = (const float*)d_in[1];   // (B,H)
    const float* X       = (const float*)d_in[2];   // (B,H,H)
    const float* U       = (const float*)d_in[3];   // (B,H,H)
    const float* raw_w_r = (const float*)d_in[4];   // (H,H)
    const float* p_r     = (const float*)d_in[5];   // (H,I)
    const float* b_r     = (const float*)d_in[6];   // (H,1)
    const float* g_z     = (const float*)d_in[7];   // (H,1)
    const float* c_x     = (const float*)d_in[8];   // (H,H)
    const float* c_u     = (const float*)d_in[9];   // (H,H)
    const float* c_U     = (const float*)d_in[10];  // (H,H)
    const float* a_exc   = (const float*)d_in[11];  // scalar
    const float* a_inh   = (const float*)d_in[12];  // scalar

    float* out = (float*)d_out;  // (B,H) fp32

    float* r_ws  = (float*)d_ws;              // B*H
    float* membx = r_ws + Bdim * Hdim;        // H*B
    float* gatex = membx + Hdim * Bdim;       // H*B
    float* t_wr  = gatex + Hdim * Bdim;       // H*H
    float* t_zx  = t_wr + (size_t)Hdim * Hdim;
    float* t_zu  = t_zx + (size_t)Hdim * Hdim;
    float* t_uc  = t_zu + (size_t)Hdim * Hdim;

    const size_t needed =
        (size_t)(3 * Bdim * Hdim + 4 * Hdim * Hdim) * sizeof(float);

    pre_kernel<<<dim3(Hdim), dim3(Bdim), 0, stream>>>(
        x, v_t, p_r, b_r, g_z, r_ws, membx, gatex);

    if (ws_size >= needed) {
        transform_kernel<<<dim3(Hdim * Hdim / (256 * 4)), dim3(256), 0, stream>>>(
            raw_w_r, c_x, c_u, c_U, t_wr, t_zx, t_zu, t_uc);
        main_kernel<true><<<dim3(Bdim / 2, Hdim / 4), dim3(256), 0, stream>>>(
            X, U, t_wr, t_zx, t_zu, t_uc, v_t, a_exc, a_inh,
            r_ws, membx, gatex, out);
    } else {
        main_kernel<false><<<dim3(Bdim / 2, Hdim / 4), dim3(256), 0, stream>>>(
            X, U, raw_w_r, c_x, c_u, c_U, v_t, a_exc, a_inh,
            r_ws, membx, gatex, out);
    }
}

// Round 4
// 594.523 us; speedup vs baseline: 1.0037x; 1.0037x over previous
//
#include <hip/hip_runtime.h>
#include <cstddef>

#define Hdim 1024
#define Bdim 64
#define Idim 128

// BETA = 10.0 / 0.192
#define BETA_F 52.083333333333336f
#define INV_BETA_F 0.0192f
#define LN2_F 0.6931471805599453f

__device__ __forceinline__ float sigf(float x) {
    return 1.0f / (1.0f + __expf(-x));
}

// log(cosh(t)) = |t| + log1p(exp(-2|t|)) - ln2   (stable, matches fp32 ref)
__device__ __forceinline__ float logcoshf_(float t) {
    float a = fabsf(t);
    return a + log1pf(__expf(-2.0f * a)) - LN2_F;
}

// ---------------------------------------------------------------------------
// Pre-kernel: rates r = sigmoid(v_t)  (flat B*H),
// and x-projections: membx[j,b] = p_r@x + b_r ; gatex[j,b] = |p_r|@x + g_z
// grid = H blocks of B threads.
// ---------------------------------------------------------------------------
__global__ void pre_kernel(const float* __restrict__ x,
                           const float* __restrict__ v_t,
                           const float* __restrict__ p_r,
                           const float* __restrict__ b_r,
                           const float* __restrict__ g_z,
                           float* __restrict__ r_ws,
                           float* __restrict__ membx,
                           float* __restrict__ gatex) {
    const int j = blockIdx.x;   // 0..H-1
    const int b = threadIdx.x;  // 0..B-1
    const float* pr = p_r + (size_t)j * Idim;
    float accm = 0.0f, accg = 0.0f;
#pragma unroll 4
    for (int i = 0; i < Idim; ++i) {
        float p  = pr[i];              // wave-uniform -> scalar load
        float xv = x[i * Bdim + b];    // coalesced
        accm = fmaf(p, xv, accm);
        accg = fmaf(fabsf(p), xv, accg);
    }
    membx[j * Bdim + b] = accm + b_r[j];
    gatex[j * Bdim + b] = accg + g_z[j];

    int id = j * Bdim + b;  // flat elementwise over B*H
    r_ws[id] = sigf(v_t[id]);
}

// ---------------------------------------------------------------------------
// Main kernel: grid (H, 2). Block (j, g): 4 waves, wave owns 8 batches of
// group g, processed as 4 batch-pairs. Per pair the wave loads ALL FOUR
// X/U rows upfront (16 independent float4 loads, 256 B/lane in flight) so
// HBM latency is hidden by load depth, not occupancy. Per-row transforms
// (logcosh/sigmoids) staged in LDS once per block. No d_ws param buffers —
// keeps HBM traffic at the X+U minimum and leaves L3 to serve restore-warm
// X/U lines.
// ---------------------------------------------------------------------------
__global__ __launch_bounds__(256, 4) void main_kernel(
    const float* __restrict__ X,
    const float* __restrict__ U,
    const float* __restrict__ raw_w_r,
    const float* __restrict__ c_x,
    const float* __restrict__ c_u,
    const float* __restrict__ c_U,
    const float* __restrict__ v_t,
    const float* __restrict__ a_exc,
    const float* __restrict__ a_inh,
    const float* __restrict__ r_ws,
    const float* __restrict__ membx,
    const float* __restrict__ gatex,
    float* __restrict__ out) {
    __shared__ __align__(16) float s_zx[Hdim];
    __shared__ __align__(16) float s_zu[Hdim];
    __shared__ __align__(16) float s_uc[Hdim];
    __shared__ __align__(16) float s_wr[Hdim];

    const int j   = blockIdx.x;
    const int tid = threadIdx.x;

    // ---- stage per-row transcendentals into LDS (256 thr x 4 elems) ----
    {
        const int k = tid * 4;
        const size_t ro = (size_t)j * Hdim + k;
        float4 rw = *(const float4*)(raw_w_r + ro);
        float4 cx = *(const float4*)(c_x + ro);
        float4 cu = *(const float4*)(c_u + ro);
        float4 cN = *(const float4*)(c_U + ro);

        s_wr[k + 0] = logcoshf_(BETA_F * rw.x) * INV_BETA_F;
        s_wr[k + 1] = logcoshf_(BETA_F * rw.y) * INV_BETA_F;
        s_wr[k + 2] = logcoshf_(BETA_F * rw.z) * INV_BETA_F;
        s_wr[k + 3] = logcoshf_(BETA_F * rw.w) * INV_BETA_F;

        s_zx[k + 0] = 0.001f + 0.099f * sigf(cx.x);
        s_zx[k + 1] = 0.001f + 0.099f * sigf(cx.y);
        s_zx[k + 2] = 0.001f + 0.099f * sigf(cx.z);
        s_zx[k + 3] = 0.001f + 0.099f * sigf(cx.w);

        s_zu[k + 0] = 0.001f + 0.099f * sigf(cu.x);
        s_zu[k + 1] = 0.001f + 0.099f * sigf(cu.y);
        s_zu[k + 2] = 0.001f + 0.099f * sigf(cu.z);
        s_zu[k + 3] = 0.001f + 0.099f * sigf(cu.w);

        s_uc[k + 0] = 0.9f * sigf(cN.x);
        s_uc[k + 1] = 0.9f * sigf(cN.y);
        s_uc[k + 2] = 0.9f * sigf(cN.z);
        s_uc[k + 3] = 0.9f * sigf(cN.w);
    }
    __syncthreads();

    const int wave = tid >> 6;
    const int lane = tid & 63;
    const int base = blockIdx.y * 32 + wave * 8;  // this wave's 8 batches

    const float Aexc = 10.0f * sigf(a_exc[0]);
    const float Ainh = 10.0f * sigf(a_inh[0]);

    for (int it = 0; it < 4; ++it) {
        const int b0 = base + 2 * it;
        const float* X0 = X + ((size_t)b0 * Hdim + j) * Hdim;
        const float* X1 = X0 + (size_t)Hdim * Hdim;
        const float* U0 = U + ((size_t)b0 * Hdim + j) * Hdim;
        const float* U1 = U0 + (size_t)Hdim * Hdim;
        const float* rr0 = r_ws + b0 * Hdim;
        const float* rr1 = rr0 + Hdim;

        // ---- issue ALL 16 HBM loads for this batch-pair back-to-back ----
        float4 xa0, xa1, xa2, xa3, ua0, ua1, ua2, ua3;
        float4 xb0, xb1, xb2, xb3, ub0, ub1, ub2, ub3;
        {
            const int k0 = lane * 4;
            xa0 = *(const float4*)(X0 + k0 + 0);
            xa1 = *(const float4*)(X0 + k0 + 256);
            xa2 = *(const float4*)(X0 + k0 + 512);
            xa3 = *(const float4*)(X0 + k0 + 768);
            ua0 = *(const float4*)(U0 + k0 + 0);
            ua1 = *(const float4*)(U0 + k0 + 256);
            ua2 = *(const float4*)(U0 + k0 + 512);
            ua3 = *(const float4*)(U0 + k0 + 768);
            xb0 = *(const float4*)(X1 + k0 + 0);
            xb1 = *(const float4*)(X1 + k0 + 256);
            xb2 = *(const float4*)(X1 + k0 + 512);
            xb3 = *(const float4*)(X1 + k0 + 768);
            ub0 = *(const float4*)(U1 + k0 + 0);
            ub1 = *(const float4*)(U1 + k0 + 256);
            ub2 = *(const float4*)(U1 + k0 + 512);
            ub3 = *(const float4*)(U1 + k0 + 768);
        }

        const float rj0 = rr0[j];
        const float rj1 = rr1[j];

        float rec0 = 0.f, rec1 = 0.f;
        float ge0 = 0.f, ge1 = 0.f;   // gate partial, k < 512 (excitatory)
        float gi0 = 0.f, gi1 = 0.f;   // gate partial, k >= 512 (inhibitory)

#define CHUNK(c, Xa, Ua, Xb, Ub, GA0, GA1)                                    \
    {                                                                         \
        const int k = c * 256 + lane * 4;                                     \
        float4 zx = *(const float4*)(s_zx + k);                               \
        float4 zu = *(const float4*)(s_zu + k);                               \
        float4 uc = *(const float4*)(s_uc + k);                               \
        float4 wr = *(const float4*)(s_wr + k);                               \
        float4 r0v = *(const float4*)(rr0 + k);                               \
        float4 r1v = *(const float4*)(rr1 + k);                               \
        float g0 = 0.f, g1 = 0.f;                                             \
        COMPONENT(x, Xa, Ua, Xb, Ub)                                          \
        COMPONENT(y, Xa, Ua, Xb, Ub)                                          \
        COMPONENT(z, Xa, Ua, Xb, Ub)                                          \
        COMPONENT(w, Xa, Ua, Xb, Ub)                                          \
        GA0 += g0;                                                            \
        GA1 += g1;                                                            \
    }
#define COMPONENT(c, Xa, Ua, Xb, Ub)                                          \
    {                                                                         \
        float xn0 = zx.c + (1.0f - zx.c) * Xa.c - Ua.c * Xa.c * rj0;          \
        float un0 = uc.c * zu.c + (1.0f - zu.c) * Ua.c +                      \
                    uc.c * (1.0f - Ua.c) * rj0;                               \
        un0 = fminf(fmaxf(un0, uc.c), 1.0f);                                  \
        rec0 = fmaf(xn0 * un0 * wr.c, r0v.c, rec0);                           \
        g0   = fmaf(wr.c, r0v.c, g0);                                         \
        float xn1 = zx.c + (1.0f - zx.c) * Xb.c - Ub.c * Xb.c * rj1;          \
        float un1 = uc.c * zu.c + (1.0f - zu.c) * Ub.c +                      \
                    uc.c * (1.0f - Ub.c) * rj1;                               \
        un1 = fminf(fmaxf(un1, uc.c), 1.0f);                                  \
        rec1 = fmaf(xn1 * un1 * wr.c, r1v.c, rec1);                           \
        g1   = fmaf(wr.c, r1v.c, g1);                                         \
    }

        CHUNK(0, xa0, ua0, xb0, ub0, ge0, ge1)
        CHUNK(1, xa1, ua1, xb1, ub1, ge0, ge1)
        CHUNK(2, xa2, ua2, xb2, ub2, gi0, gi1)
        CHUNK(3, xa3, ua3, xb3, ub3, gi0, gi1)
#undef COMPONENT
#undef CHUNK

        float gate0 = fmaf(Aexc, ge0, Ainh * gi0);
        float gate1 = fmaf(Aexc, ge1, Ainh * gi1);

#pragma unroll
        for (int off = 32; off > 0; off >>= 1) {
            rec0  += __shfl_xor(rec0, off, 64);
            rec1  += __shfl_xor(rec1, off, 64);
            gate0 += __shfl_xor(gate0, off, 64);
            gate1 += __shfl_xor(gate1, off, 64);
        }

        if (lane == 0) {
            {
                float z  = 0.1f * sigf(gate0 + gatex[j * Bdim + b0]);
                float vt = v_t[(size_t)b0 * Hdim + j];
                out[(size_t)b0 * Hdim + j] =
                    (1.0f - z) * vt + 0.1f * (rec0 + membx[j * Bdim + b0]);
            }
            {
                const int b = b0 + 1;
                float z  = 0.1f * sigf(gate1 + gatex[j * Bdim + b]);
                float vt = v_t[(size_t)b * Hdim + j];
                out[(size_t)b * Hdim + j] =
                    (1.0f - z) * vt + 0.1f * (rec1 + membx[j * Bdim + b]);
            }
        }
    }
}

extern "C" void kernel_launch(void* const* d_in, const int* in_sizes, int n_in,
                              void* d_out, int out_size, void* d_ws, size_t ws_size,
                              hipStream_t stream) {
    const float* x       = (const float*)d_in[0];   // (I,B)
    const float* v_t     = (const float*)d_in[1];   // (B,H)
    const float* X       = (const float*)d_in[2];   // (B,H,H)
    const float* U       = (const float*)d_in[3];   // (B,H,H)
    const float* raw_w_r = (const float*)d_in[4];   // (H,H)
    const float* p_r     = (const float*)d_in[5];   // (H,I)
    const float* b_r     = (const float*)d_in[6];   // (H,1)
    const float* g_z     = (const float*)d_in[7];   // (H,1)
    const float* c_x     = (const float*)d_in[8];   // (H,H)
    const float* c_u     = (const float*)d_in[9];   // (H,H)
    const float* c_U     = (const float*)d_in[10];  // (H,H)
    const float* a_exc   = (const float*)d_in[11];  // scalar
    const float* a_inh   = (const float*)d_in[12];  // scalar

    float* out = (float*)d_out;  // (B,H) fp32

    float* r_ws  = (float*)d_ws;              // B*H
    float* membx = r_ws + Bdim * Hdim;        // H*B
    float* gatex = membx + Hdim * Bdim;       // H*B

    pre_kernel<<<dim3(Hdim), dim3(Bdim), 0, stream>>>(
        x, v_t, p_r, b_r, g_z, r_ws, membx, gatex);

    main_kernel<<<dim3(Hdim, 2), dim3(256), 0, stream>>>(
        X, U, raw_w_r, c_x, c_u, c_U, v_t, a_exc, a_inh,
        r_ws, membx, gatex, out);
}

// Round 5
// 577.165 us; speedup vs baseline: 1.0339x; 1.0301x over previous
//
#include <hip/hip_runtime.h>
#include <cstddef>

#define Hdim 1024
#define Bdim 64
#define Idim 128

// BETA = 10.0 / 0.192
#define BETA_F 52.083333333333336f
#define INV_BETA_F 0.0192f
#define LN2_F 0.6931471805599453f

__device__ __forceinline__ float sigf(float x) {
    return 1.0f / (1.0f + __expf(-x));
}

// log(cosh(t)) = |t| + log1p(exp(-2|t|)) - ln2   (stable, matches fp32 ref)
__device__ __forceinline__ float logcoshf_(float t) {
    float a = fabsf(t);
    return a + log1pf(__expf(-2.0f * a)) - LN2_F;
}

// ---------------------------------------------------------------------------
// Pre-kernel: rates r = sigmoid(v_t)  (flat B*H),
// and x-projections: membx[j,b] = p_r@x + b_r ; gatex[j,b] = |p_r|@x + g_z
// grid = H blocks of B threads.
// ---------------------------------------------------------------------------
__global__ void pre_kernel(const float* __restrict__ x,
                           const float* __restrict__ v_t,
                           const float* __restrict__ p_r,
                           const float* __restrict__ b_r,
                           const float* __restrict__ g_z,
                           float* __restrict__ r_ws,
                           float* __restrict__ membx,
                           float* __restrict__ gatex) {
    const int j = blockIdx.x;   // 0..H-1
    const int b = threadIdx.x;  // 0..B-1
    const float* pr = p_r + (size_t)j * Idim;
    float accm = 0.0f, accg = 0.0f;
#pragma unroll 4
    for (int i = 0; i < Idim; ++i) {
        float p  = pr[i];              // wave-uniform -> scalar load
        float xv = x[i * Bdim + b];    // coalesced
        accm = fmaf(p, xv, accm);
        accg = fmaf(fabsf(p), xv, accg);
    }
    membx[j * Bdim + b] = accm + b_r[j];
    gatex[j * Bdim + b] = accg + g_z[j];

    int id = j * Bdim + b;  // flat elementwise over B*H
    r_ws[id] = sigf(v_t[id]);
}

// ---------------------------------------------------------------------------
// Main kernel: pure streaming, no LDS, no barriers (R3 structure — best
// measured BW 3.2 TB/s) but with param transforms computed INLINE from the
// raw matrices (no d_ws buffers) so HBM traffic stays at the ~300 MB floor
// (X/U partially L3-warm from the harness restore + 16 MB raw params).
// Grid (32, 256): blockIdx.x = batch-pair (b0 = 2*x), blockIdx.y = j-quad;
// x-major dispatch means concurrent blocks share the same j param rows in
// L2/L3. Each of the 4 waves owns one j-row and streams 2 batches' X/U rows.
// The redundant transcendentals (~14 µs of quarter-rate VALU chip-wide)
// overlap with memory latency — R3's VALUBusy was only 18%.
// __launch_bounds__(256,6): VGPR cap 85 — room for transcendental temps +
// pipelined loads without spilling.
// ---------------------------------------------------------------------------
__global__ __launch_bounds__(256, 6) void main_kernel(
    const float* __restrict__ X,
    const float* __restrict__ U,
    const float* __restrict__ raw_w_r,
    const float* __restrict__ c_x,
    const float* __restrict__ c_u,
    const float* __restrict__ c_U,
    const float* __restrict__ v_t,
    const float* __restrict__ a_exc,
    const float* __restrict__ a_inh,
    const float* __restrict__ r_ws,
    const float* __restrict__ membx,
    const float* __restrict__ gatex,
    float* __restrict__ out) {
    const int wave = threadIdx.x >> 6;
    const int lane = threadIdx.x & 63;
    const int j    = blockIdx.y * 4 + wave;
    const int b0   = blockIdx.x * 2;

    const size_t prow = (size_t)j * Hdim;
    const float* pw  = raw_w_r + prow;
    const float* pzx = c_x + prow;
    const float* pzu = c_u + prow;
    const float* puc = c_U + prow;

    const float* X0 = X + ((size_t)b0 * Hdim + j) * Hdim;
    const float* X1 = X0 + (size_t)Hdim * Hdim;
    const float* U0 = U + ((size_t)b0 * Hdim + j) * Hdim;
    const float* U1 = U0 + (size_t)Hdim * Hdim;
    const float* rr0 = r_ws + b0 * Hdim;
    const float* rr1 = rr0 + Hdim;

    const float rj0 = rr0[j];
    const float rj1 = rr1[j];

    float rec0 = 0.f, rec1 = 0.f;
    float ge0 = 0.f, ge1 = 0.f;   // gate partial, k < 512 (excitatory)
    float gi0 = 0.f, gi1 = 0.f;   // gate partial, k >= 512 (inhibitory)

#pragma unroll
    for (int chunk = 0; chunk < 4; ++chunk) {
        const int k = (chunk * 64 + lane) * 4;
        float4 rw = *(const float4*)(pw + k);
        float4 cx = *(const float4*)(pzx + k);
        float4 cu = *(const float4*)(pzu + k);
        float4 cN = *(const float4*)(puc + k);
        float4 r0 = *(const float4*)(rr0 + k);
        float4 r1 = *(const float4*)(rr1 + k);
        float4 Xv0 = *(const float4*)(X0 + k);
        float4 Uv0 = *(const float4*)(U0 + k);
        float4 Xv1 = *(const float4*)(X1 + k);
        float4 Uv1 = *(const float4*)(U1 + k);

        float4 wr, zx, zu, uc;
        wr.x = logcoshf_(BETA_F * rw.x) * INV_BETA_F;
        wr.y = logcoshf_(BETA_F * rw.y) * INV_BETA_F;
        wr.z = logcoshf_(BETA_F * rw.z) * INV_BETA_F;
        wr.w = logcoshf_(BETA_F * rw.w) * INV_BETA_F;
        zx.x = 0.001f + 0.099f * sigf(cx.x);
        zx.y = 0.001f + 0.099f * sigf(cx.y);
        zx.z = 0.001f + 0.099f * sigf(cx.z);
        zx.w = 0.001f + 0.099f * sigf(cx.w);
        zu.x = 0.001f + 0.099f * sigf(cu.x);
        zu.y = 0.001f + 0.099f * sigf(cu.y);
        zu.z = 0.001f + 0.099f * sigf(cu.z);
        zu.w = 0.001f + 0.099f * sigf(cu.w);
        uc.x = 0.9f * sigf(cN.x);
        uc.y = 0.9f * sigf(cN.y);
        uc.z = 0.9f * sigf(cN.z);
        uc.w = 0.9f * sigf(cN.w);

        float g0 = 0.f, g1 = 0.f;
#define COMPONENT(c)                                                          \
    {                                                                         \
        float xn0 = zx.c + (1.0f - zx.c) * Xv0.c - Uv0.c * Xv0.c * rj0;       \
        float un0 = uc.c * zu.c + (1.0f - zu.c) * Uv0.c +                     \
                    uc.c * (1.0f - Uv0.c) * rj0;                              \
        un0 = fminf(fmaxf(un0, uc.c), 1.0f);                                  \
        rec0 = fmaf(xn0 * un0 * wr.c, r0.c, rec0);                            \
        g0   = fmaf(wr.c, r0.c, g0);                                          \
        float xn1 = zx.c + (1.0f - zx.c) * Xv1.c - Uv1.c * Xv1.c * rj1;       \
        float un1 = uc.c * zu.c + (1.0f - zu.c) * Uv1.c +                     \
                    uc.c * (1.0f - Uv1.c) * rj1;                              \
        un1 = fminf(fmaxf(un1, uc.c), 1.0f);                                  \
        rec1 = fmaf(xn1 * un1 * wr.c, r1.c, rec1);                            \
        g1   = fmaf(wr.c, r1.c, g1);                                          \
    }
        COMPONENT(x)
        COMPONENT(y)
        COMPONENT(z)
        COMPONENT(w)
#undef COMPONENT
        if (chunk < 2) { ge0 += g0; ge1 += g1; }
        else           { gi0 += g0; gi1 += g1; }
    }

    // fold Dale gains, then butterfly-reduce 4 values across the wave
    const float Aexc = 10.0f * sigf(a_exc[0]);
    const float Ainh = 10.0f * sigf(a_inh[0]);
    float gate0 = fmaf(Aexc, ge0, Ainh * gi0);
    float gate1 = fmaf(Aexc, ge1, Ainh * gi1);

#pragma unroll
    for (int off = 32; off > 0; off >>= 1) {
        rec0  += __shfl_xor(rec0, off, 64);
        rec1  += __shfl_xor(rec1, off, 64);
        gate0 += __shfl_xor(gate0, off, 64);
        gate1 += __shfl_xor(gate1, off, 64);
    }

    if (lane == 0) {
        {
            float z  = 0.1f * sigf(gate0 + gatex[j * Bdim + b0]);
            float vt = v_t[(size_t)b0 * Hdim + j];
            out[(size_t)b0 * Hdim + j] =
                (1.0f - z) * vt + 0.1f * (rec0 + membx[j * Bdim + b0]);
        }
        {
            const int b = b0 + 1;
            float z  = 0.1f * sigf(gate1 + gatex[j * Bdim + b]);
            float vt = v_t[(size_t)b * Hdim + j];
            out[(size_t)b * Hdim + j] =
                (1.0f - z) * vt + 0.1f * (rec1 + membx[j * Bdim + b]);
        }
    }
}

extern "C" void kernel_launch(void* const* d_in, const int* in_sizes, int n_in,
                              void* d_out, int out_size, void* d_ws, size_t ws_size,
                              hipStream_t stream) {
    const float* x       = (const float*)d_in[0];   // (I,B)
    const float* v_t     = (const float*)d_in[1];   // (B,H)
    const float* X       = (const float*)d_in[2];   // (B,H,H)
    const float* U       = (const float*)d_in[3];   // (B,H,H)
    const float* raw_w_r = (const float*)d_in[4];   // (H,H)
    const float* p_r     = (const float*)d_in[5];   // (H,I)
    const float* b_r     = (const float*)d_in[6];   // (H,1)
    const float* g_z     = (const float*)d_in[7];   // (H,1)
    const float* c_x     = (const float*)d_in[8];   // (H,H)
    const float* c_u     = (const float*)d_in[9];   // (H,H)
    const float* c_U     = (const float*)d_in[10];  // (H,H)
    const float* a_exc   = (const float*)d_in[11];  // scalar
    const float* a_inh   = (const float*)d_in[12];  // scalar

    float* out = (float*)d_out;  // (B,H) fp32

    float* r_ws  = (float*)d_ws;              // B*H
    float* membx = r_ws + Bdim * Hdim;        // H*B
    float* gatex = membx + Hdim * Bdim;       // H*B

    pre_kernel<<<dim3(Hdim), dim3(Bdim), 0, stream>>>(
        x, v_t, p_r, b_r, g_z, r_ws, membx, gatex);

    main_kernel<<<dim3(Bdim / 2, Hdim / 4), dim3(256), 0, stream>>>(
        X, U, raw_w_r, c_x, c_u, c_U, v_t, a_exc, a_inh,
        r_ws, membx, gatex, out);
}